// Round 16
// baseline (539.369 us; speedup 1.0000x reference)
//
#include <hip/hip_runtime.h>
#include <hip/hip_bf16.h>
#include <math.h>

#define N_NODES 100000
#define N_EDGES 1600000
#define H 10
#define HID 64
#define E2 (2 * N_EDGES)          // 3,200,000

// two-level counting sort: 391 buckets of 256 nodes (b = src >> 8)
#define NBKT 391                  // ceil(100000/256)
#define NCHUNK 256
#define CHUNK (E2 / NCHUNK)       // 12500 exact
#define BKT_CAP 12032             // LDS staging cap (mean 8192, sigma ~90)
#define NODE_BLOCKS ((N_NODES + 255) / 256)   // 391

typedef __attribute__((ext_vector_type(8))) short short8;
typedef __attribute__((ext_vector_type(4))) float f32x4;
typedef __attribute__((ext_vector_type(2))) unsigned int uint2v;
typedef __attribute__((ext_vector_type(4))) unsigned int uint4v;
typedef unsigned int uint4u __attribute__((ext_vector_type(4), aligned(4)));

#define MFMA16(a, b, c) __builtin_amdgcn_mfma_f32_16x16x32_bf16((a), (b), (c), 0, 0, 0)

__device__ __forceinline__ float sigmoidf_(float x) {
    return 1.0f / (1.0f + __expf(-x));
}
__device__ __forceinline__ float tanhf_(float x) {
    float ax = fabsf(x);
    float t = 1.0f - 2.0f / (__expf(2.0f * ax) + 1.0f);
    return copysignf(t, x);
}
__device__ __forceinline__ unsigned short f2bf(float f) {
    union { __hip_bfloat16 b; unsigned short u; } cv;
    cv.b = __float2bfloat16(f);   // RNE, NaN-safe (cold paths only)
    return cv.u;
}
__device__ __forceinline__ unsigned pack2(float lo, float hi) {
    return (unsigned)f2bf(lo) | ((unsigned)f2bf(hi) << 16);
}
// hot-path packed cvt: 1 inst, RNE; inputs guaranteed finite (post-relu)
__device__ __forceinline__ unsigned cvt_pk(float lo, float hi) {
    unsigned r;
    asm("v_cvt_pk_bf16_f32 %0, %1, %2" : "=v"(r) : "v"(lo), "v"(hi));
    return r;
}
__device__ __forceinline__ int2 ll2int2(long long v) {
    int2 r;
    r.x = (int)(v & 0xffffffffll);   // src in low word
    r.y = (int)(v >> 32);            // dst in high word
    return r;
}

// ---------------- CSR build: deterministic counting sort --------------------

__global__ __launch_bounds__(256) void binhist_kernel(
    const int* __restrict__ edges, int* __restrict__ cntmat, int* __restrict__ done)
{
    if (blockIdx.x == 0 && threadIdx.x == 0) *done = 0;   // reset for fused scan
    __shared__ int cnt[NBKT];
    for (int i = threadIdx.x; i < NBKT; i += 256) cnt[i] = 0;
    __syncthreads();
    const int c = blockIdx.x, lo = c * CHUNK;
    for (int i = threadIdx.x; i < CHUNK; i += 256) {
        int s = edges[lo + i];
        atomicAdd(&cnt[s >> 8], 1);
    }
    __syncthreads();
    for (int i = threadIdx.x; i < NBKT; i += 256) cntmat[i * NCHUNK + c] = cnt[i];
}

// per-bucket scan over chunk counts; LAST block also scans bucket totals into
// bases (fused basescan: last-block-done pattern, device-scope)
__global__ __launch_bounds__(256) void bucketscan_kernel(
    const int* __restrict__ cntmat, int* __restrict__ offmat,
    int* __restrict__ totals, int* __restrict__ bases, int* __restrict__ done)
{
    __shared__ int s[NCHUNK];
    __shared__ int amLast;
    const int b = blockIdx.x, tid = threadIdx.x;
    int v = cntmat[b * NCHUNK + tid];
    s[tid] = v;
    __syncthreads();
    for (int off = 1; off < 256; off <<= 1) {
        int t = (tid >= off) ? s[tid - off] : 0;
        __syncthreads();
        s[tid] += t;
        __syncthreads();
    }
    offmat[b * NCHUNK + tid] = s[tid] - v;
    if (tid == 255) totals[b] = s[255];
    __syncthreads();
    if (tid == 0) {
        __threadfence();
        amLast = (atomicAdd(done, 1) == NBKT - 1);
    }
    __syncthreads();
    if (!amLast) return;
    // ---- fused basescan (only the last-finished block) ----
    int i0 = 2 * tid, i1 = 2 * tid + 1;
    int t0 = (i0 < NBKT) ? atomicAdd(&totals[i0], 0) : 0;
    int t1 = (i1 < NBKT) ? atomicAdd(&totals[i1], 0) : 0;
    int sum = t0 + t1;
    s[tid] = sum;
    __syncthreads();
    for (int off = 1; off < 256; off <<= 1) {
        int t = (tid >= off) ? s[tid - off] : 0;
        __syncthreads();
        s[tid] += t;
        __syncthreads();
    }
    int run = s[tid] - sum;
    if (i0 < NBKT) bases[i0] = run;
    if (i1 < NBKT) bases[i1] = run + t0;
}

__global__ __launch_bounds__(256) void binscatter_kernel(
    const int* __restrict__ edges, const int* __restrict__ offmat,
    const int* __restrict__ bases, long long* __restrict__ pairsLL)
{
    __shared__ int cursor[NBKT];
    const int c = blockIdx.x, lo = c * CHUNK;
    for (int i = threadIdx.x; i < NBKT; i += 256)
        cursor[i] = bases[i] + offmat[i * NCHUNK + c];
    __syncthreads();
    for (int i = threadIdx.x; i < CHUNK; i += 256) {
        int e = lo + i;
        int s = edges[e];
        int d = (e < N_EDGES) ? edges[e + N_EDGES] : edges[e - N_EDGES];
        int pos = atomicAdd(&cursor[s >> 8], 1);   // LDS atomic
        pairsLL[pos] = (long long)(unsigned)s | ((long long)d << 32);
    }
}

__global__ __launch_bounds__(256) void bucketsort_kernel(
    const int* __restrict__ totals, const int* __restrict__ bases,
    long long* __restrict__ pairsLL)
{
    __shared__ long long sE[BKT_CAP];
    __shared__ int cnt[256];
    __shared__ int cur[256];
    const int b = blockIdx.x, tid = threadIdx.x;
    const int tot = totals[b], base = bases[b];
    if (tot > BKT_CAP) return;   // unsorted bucket still CORRECT (order-agnostic reduce)
    for (int i = tid; i < tot; i += 256) sE[i] = pairsLL[base + i];
    cnt[tid] = 0;
    __syncthreads();
    for (int i = tid; i < tot; i += 256)
        atomicAdd(&cnt[((int)sE[i]) & 255], 1);
    __syncthreads();
    int v = cnt[tid];
    cur[tid] = v;
    __syncthreads();
    for (int off = 1; off < 256; off <<= 1) {
        int t = (tid >= off) ? cur[tid - off] : 0;
        __syncthreads();
        cur[tid] += t;
        __syncthreads();
    }
    cnt[tid] = cur[tid] - v;
    __syncthreads();
    for (int i = tid; i < tot; i += 256) {
        long long e = sE[i];
        int r = atomicAdd(&cnt[((int)e) & 255], 1);
        pairsLL[base + r] = e;
    }
}

// ---------------- one-time precompute (merged prep+convert+zero-a) ----------

#define WBUF_B3_OFF 14336   // 14*64*16

__global__ __launch_bounds__(256) void prep_convert_kernel(
    const float* __restrict__ h, unsigned char* __restrict__ hbf,
    float* __restrict__ a,
    const float* __restrict__ W1, const float* __restrict__ b1,
    const float* __restrict__ W2,
    const float* __restrict__ W3, const float* __restrict__ b3,
    unsigned char* __restrict__ wbuf)
{
    const int blk = blockIdx.x;
    if (blk < NODE_BLOCKS) {
        int n = blk * 256 + threadIdx.x;
        if (n >= N_NODES) return;
        const float* r = h + (size_t)n * 10;
        unsigned w0 = pack2(r[0], r[1]), w1 = pack2(r[2], r[3]), w2 = pack2(r[4], r[5]),
                 w3 = pack2(r[6], r[7]), w4 = pack2(r[8], r[9]);
        unsigned char* o = hbf + (size_t)n * 20;
        *(uint4u*)o = (uint4u){w0, w1, w2, w3};
        *(unsigned int*)(o + 16) = w4;
        float2* az = (float2*)(a + (size_t)n * 10);
        float2 z = make_float2(0.0f, 0.0f);
        az[0] = z; az[1] = z; az[2] = z; az[3] = z; az[4] = z;
        return;
    }
    int idx = (blk - NODE_BLOCKS) * 256 + threadIdx.x;
    if (idx < 896) {
        int f = idx >> 6, l = idx & 63, l15 = l & 15, lo4 = l >> 4;
        unsigned short v[8];
        #pragma unroll
        for (int i = 0; i < 8; ++i) {
            int kk = lo4 * 8 + i;
            float val = 0.0f;
            if (f < 4) {
                int row = f * 16 + l15;
                val = (kk < 20) ? W1[row * 20 + kk] : (kk == 20 ? b1[row] : 0.0f);
            } else if (f < 12) {
                int g = f - 4, nt = g >> 1, ks = g & 1;
                val = W2[(nt * 16 + l15) * 64 + ks * 32 + kk];
            } else {
                int ks = f - 12;
                val = (l15 < 10) ? W3[l15 * 64 + ks * 32 + kk] : 0.0f;
            }
            v[i] = f2bf(val);
        }
        uint4v pk = { (unsigned)v[0] | ((unsigned)v[1] << 16),
                      (unsigned)v[2] | ((unsigned)v[3] << 16),
                      (unsigned)v[4] | ((unsigned)v[5] << 16),
                      (unsigned)v[6] | ((unsigned)v[7] << 16) };
        *(uint4v*)(wbuf + (size_t)idx * 16) = pk;
    } else if (idx < 896 + 16) {
        int o = idx - 896;
        *(float*)(wbuf + WBUF_B3_OFF + o * 4) = (o < 10) ? b3[o] : 0.0f;
    }
}

// ---------------- MFMA edge MLP ---------------------------------------------
// 256 threads = 4 waves; block handles 256 src-sorted edges. Wave w owns LDS
// rows [w*64, w*64+64) exclusively -> ZERO barriers. Wave-local segments,
// head list in registers (ballot + ds_permute), wave-uniform reduce loop.
// Reduce phase reads f32x4 per row (b128) per (segment, feature-group):
// 3 groups/segment (feats 0-3, 4-7, 8-9); group 2 adds only 2 elements
// (elements 2,3 are the zero-padded features 10,11 — adding them would
// corrupt the NEXT node's a[0..1]).

__global__ __launch_bounds__(256) void edge_mlp_mfma2_kernel(
    const unsigned char* __restrict__ hbf,   // [N][20B] bf16
    const long long* __restrict__ pairsLL,
    const unsigned char* __restrict__ wbuf,
    const float* __restrict__ b2,
    float* __restrict__ a)
{
    __shared__ __align__(16) unsigned char sX[256 * 128];   // exactly 32 KiB

    char* sXp = (char*)sX;
    const int t = threadIdx.x;
    const int w = t >> 6, l = t & 63, l15 = l & 15, lo4 = l >> 4;
    const int mbase = w * 64;

    short8 W1f[4], W2f[4][2], W3f[2];
    #pragma unroll
    for (int nt = 0; nt < 4; ++nt)
        W1f[nt] = *(const short8*)(wbuf + ((nt * 64 + l) << 4));
    #pragma unroll
    for (int nt = 0; nt < 4; ++nt)
        #pragma unroll
        for (int ks = 0; ks < 2; ++ks)
            W2f[nt][ks] = *(const short8*)(wbuf + (((4 + nt * 2 + ks) * 64 + l) << 4));
    #pragma unroll
    for (int ks = 0; ks < 2; ++ks)
        W3f[ks] = *(const short8*)(wbuf + (((12 + ks) * 64 + l) << 4));
    f32x4 bb2[4];
    #pragma unroll
    for (int nt = 0; nt < 4; ++nt)
        bb2[nt] = *(const f32x4*)(b2 + nt * 16 + lo4 * 4);
    const f32x4 bb3 = *(const f32x4*)((const float*)(wbuf + WBUF_B3_OFF) + lo4 * 4);

    // ---- gather (single pairs load; predecessor via shfl_up)
    const int k = blockIdx.x * 256 + t;
    const int2 p = ll2int2(pairsLL[k]);
    const int pmx = __shfl_up(p.x, 1);
    const bool head = ((l & 15) == 0) || (pmx != p.x);

    const unsigned char* sp = hbf + (size_t)p.x * 20;
    const unsigned char* dp = hbf + (size_t)p.y * 20;
    uint4u s4 = *(const uint4u*)sp;
    unsigned int st = *(const unsigned int*)(sp + 16);
    uint4u d4 = *(const uint4u*)dp;
    unsigned int dt = *(const unsigned int*)(dp + 16);

    {
        char* row = sXp + (t << 7);
        const int sw = (t & 7) << 4;
        *(uint4v*)(row + (0  ^ sw)) = (uint4v){s4.x, s4.y, s4.z, s4.w};
        *(uint4v*)(row + (16 ^ sw)) = (uint4v){st, d4.x, d4.y, d4.z};
        *(uint4v*)(row + (32 ^ sw)) = (uint4v){d4.w, dt, 0x00003F80u, 0u};
        *(uint4v*)(row + (48 ^ sw)) = (uint4v){0u, 0u, 0u, 0u};
    }
    // no barrier anywhere: wave touches only its own 64 rows

    const int srow = (l15 & 7) << 4;

    __builtin_amdgcn_s_setprio(1);

    // ---- GEMM1: K=32; bias embedded in W1 col 20
    #pragma unroll
    for (int mt = 0; mt < 4; ++mt) {
        const int rb = (mbase + mt * 16 + l15) << 7;
        short8 Bf = *(const short8*)(sXp + rb + ((lo4 << 4) ^ srow));
        #pragma unroll
        for (int nt = 0; nt < 4; ++nt) {
            f32x4 acc = {0.0f, 0.0f, 0.0f, 0.0f};
            acc = MFMA16(W1f[nt], Bf, acc);
            acc[0] = fmaxf(acc[0], 0.0f); acc[1] = fmaxf(acc[1], 0.0f);
            acc[2] = fmaxf(acc[2], 0.0f); acc[3] = fmaxf(acc[3], 0.0f);
            uint2v pk = { cvt_pk(acc[0], acc[1]), cvt_pk(acc[2], acc[3]) };
            const int jy = (nt * 2 + (lo4 >> 1)) << 4;
            *(uint2v*)(sXp + rb + (jy ^ srow) + ((lo4 & 1) << 3)) = pk;
        }
    }

    // ---- GEMM2: K=64, bias b2
    #pragma unroll
    for (int mt = 0; mt < 4; ++mt) {
        const int rb = (mbase + mt * 16 + l15) << 7;
        short8 B0 = *(const short8*)(sXp + rb + ((lo4 << 4) ^ srow));
        short8 B1 = *(const short8*)(sXp + rb + (((4 + lo4) << 4) ^ srow));
        #pragma unroll
        for (int nt = 0; nt < 4; ++nt) {
            f32x4 acc = bb2[nt];
            acc = MFMA16(W2f[nt][0], B0, acc);
            acc = MFMA16(W2f[nt][1], B1, acc);
            acc[0] = fmaxf(acc[0], 0.0f); acc[1] = fmaxf(acc[1], 0.0f);
            acc[2] = fmaxf(acc[2], 0.0f); acc[3] = fmaxf(acc[3], 0.0f);
            uint2v pk = { cvt_pk(acc[0], acc[1]), cvt_pk(acc[2], acc[3]) };
            const int jy = (nt * 2 + (lo4 >> 1)) << 4;
            *(uint2v*)(sXp + rb + (jy ^ srow) + ((lo4 & 1) << 3)) = pk;
        }
    }

    // ---- GEMM3: 16 out-feats (10 valid, 10-15 exactly zero), K=64
    #pragma unroll
    for (int mt = 0; mt < 4; ++mt) {
        const int rb = (mbase + mt * 16 + l15) << 7;
        short8 B0 = *(const short8*)(sXp + rb + ((lo4 << 4) ^ srow));
        short8 B1 = *(const short8*)(sXp + rb + (((4 + lo4) << 4) ^ srow));
        f32x4 acc = bb3;
        acc = MFMA16(W3f[0], B0, acc);
        acc = MFMA16(W3f[1], B1, acc);
        *(f32x4*)(sXp + rb + ((lo4 << 4) ^ srow)) = acc;
    }

    __builtin_amdgcn_s_setprio(0);

    // ---- wave-local segmented reduction (no barriers, wave-uniform loop)
    // work item = (segment, feature-group); group reads f32x4 per row (b128)
    unsigned long long m = __ballot(head);
    const int nseg = __popcll(m);                       // wave-uniform
    const int rank = __popcll(m & ((1ull << l) - 1ull));
    const int hp = __builtin_amdgcn_ds_permute((head ? rank : 63) << 2, l);

    const int total = nseg * 3;                         // wave-uniform
    const int niter = (total + 63) >> 6;                // 1..2
    for (int it2 = 0; it2 < niter; ++it2) {
        const int q = it2 * 64 + l;
        const bool live = (q < total);
        const int qa = live ? q : (total - 1);          // clamp: keep lane active
        const int seg = qa / 3;
        const int g = qa - seg * 3;
        const int segn = (seg + 1 < nseg) ? (seg + 1) : seg;
        const int r0 = __shfl(hp, seg);                 // all 64 lanes active
        const int rn = __shfl(hp, segn);
        const int r1 = (seg + 1 < nseg) ? rn : 64;
        const int node = __shfl(p.x, r0);
        const int gb = g << 4;                          // byte offset of group
        f32x4 acc4 = {0.0f, 0.0f, 0.0f, 0.0f};
        for (int r = r0; r < r1; ++r) {
            int row = mbase + r;
            acc4 += *(const f32x4*)(sXp + (row << 7) + (gb ^ ((row & 7) << 4)));
        }
        if (live) {
            float* an = a + (size_t)node * H + g * 4;
            const int jmax = (g == 2) ? 2 : 4;          // mask zero-pad feats 10,11
            #pragma unroll
            for (int j = 0; j < 4; ++j)
                if (j < jmax) atomicAdd(an + j, acc4[j]);
        }
    }
}

// ---------------- fallback VALU edge kernel (no workspace) ------------------

__global__ __launch_bounds__(256) void edge_mlp_kernel(
    const float* __restrict__ h,
    const int*   __restrict__ edges,
    const float* __restrict__ W1, const float* __restrict__ b1,
    const float* __restrict__ W2, const float* __restrict__ b2,
    const float* __restrict__ W3, const float* __restrict__ b3,
    float* __restrict__ a)
{
    __shared__ float sW1T[2 * H * HID];
    __shared__ float sb1[HID];
    __shared__ float sW2[HID * HID];
    __shared__ float sb2[HID];
    __shared__ float sW3T[HID * H];
    __shared__ float sb3[H];
    for (int i = threadIdx.x; i < 2 * H * HID; i += blockDim.x) {
        int kk = i >> 6, j = i & 63;
        sW1T[i] = W1[j * (2 * H) + kk];
    }
    for (int i = threadIdx.x; i < HID * HID; i += blockDim.x) sW2[i] = W2[i];
    for (int i = threadIdx.x; i < HID * H; i += blockDim.x) {
        int j = i / H, o = i - j * H;
        sW3T[i] = W3[o * HID + j];
    }
    if (threadIdx.x < HID) { sb1[threadIdx.x] = b1[threadIdx.x]; sb2[threadIdx.x] = b2[threadIdx.x]; }
    if (threadIdx.x < H)   { sb3[threadIdx.x] = b3[threadIdx.x]; }
    __syncthreads();
    int e = blockIdx.x * blockDim.x + threadIdx.x;
    if (e >= E2) return;
    int s = edges[e];
    int d = (e < N_EDGES) ? edges[N_EDGES + e] : edges[e - N_EDGES];
    const float* hs = h + (size_t)s * H;
    const float* hd = h + (size_t)d * H;
    float m1[HID];
    #pragma unroll
    for (int j = 0; j < HID; ++j) m1[j] = sb1[j];
    for (int kk = 0; kk < H; ++kk) {
        float xs = hs[kk], xd = hd[kk];
        const float* w_s = &sW1T[kk * HID];
        const float* w_d = &sW1T[(H + kk) * HID];
        #pragma unroll
        for (int j = 0; j < HID; ++j) {
            m1[j] = fmaf(w_s[j], xs, m1[j]);
            m1[j] = fmaf(w_d[j], xd, m1[j]);
        }
    }
    #pragma unroll
    for (int j = 0; j < HID; ++j) m1[j] = fmaxf(m1[j], 0.0f);
    float out[H];
    #pragma unroll
    for (int o = 0; o < H; ++o) out[o] = sb3[o];
    for (int j = 0; j < HID; ++j) {
        float acc = sb2[j];
        const float* wv = &sW2[j * HID];
        #pragma unroll
        for (int kk = 0; kk < HID; ++kk) acc = fmaf(wv[kk], m1[kk], acc);
        acc = fmaxf(acc, 0.0f);
        const float* w3 = &sW3T[j * H];
        #pragma unroll
        for (int o = 0; o < H; ++o) out[o] = fmaf(w3[o], acc, out[o]);
    }
    float* as = a + (size_t)s * H;
    #pragma unroll
    for (int o = 0; o < H; ++o) atomicAdd(&as[o], out[o]);
}

// ---------------- GRU (+ bf16 h epilogue + a re-zero) -----------------------

__global__ __launch_bounds__(256) void gru_kernel(
    const float* __restrict__ h_in,
    float* __restrict__ a,               // read, then zeroed for next iter
    float* __restrict__ h_out,
    const float* __restrict__ W_ih, const float* __restrict__ b_ih,
    const float* __restrict__ W_hh, const float* __restrict__ b_hh,
    unsigned char* __restrict__ hbf)
{
    __shared__ float sWih[3 * H * H];
    __shared__ float sWhh[3 * H * H];
    __shared__ float sbih[3 * H];
    __shared__ float sbhh[3 * H];
    for (int i = threadIdx.x; i < 3 * H * H; i += blockDim.x) { sWih[i] = W_ih[i]; sWhh[i] = W_hh[i]; }
    if (threadIdx.x < 3 * H) { sbih[threadIdx.x] = b_ih[threadIdx.x]; sbhh[threadIdx.x] = b_hh[threadIdx.x]; }
    __syncthreads();

    int n = blockIdx.x * blockDim.x + threadIdx.x;
    if (n >= N_NODES) return;

    float av[H], hv[H];
    #pragma unroll
    for (int kk = 0; kk < H; ++kk) { av[kk] = a[(size_t)n * H + kk]; hv[kk] = h_in[(size_t)n * H + kk]; }
    #pragma unroll
    for (int kk = 0; kk < H; ++kk) a[(size_t)n * H + kk] = 0.0f;   // re-zero for next iter

    float gi[3 * H], gh[3 * H];
    #pragma unroll
    for (int g = 0; g < 3 * H; ++g) {
        float ai = sbih[g], hh = sbhh[g];
        const float* wi = &sWih[g * H];
        const float* wh = &sWhh[g * H];
        #pragma unroll
        for (int kk = 0; kk < H; ++kk) {
            ai = fmaf(wi[kk], av[kk], ai);
            hh = fmaf(wh[kk], hv[kk], hh);
        }
        gi[g] = ai; gh[g] = hh;
    }

    float ho[H];
    #pragma unroll
    for (int o = 0; o < H; ++o) {
        float r = sigmoidf_(gi[o] + gh[o]);
        float z = sigmoidf_(gi[H + o] + gh[H + o]);
        float nn = tanhf_(gi[2 * H + o] + r * gh[2 * H + o]);
        ho[o] = (1.0f - z) * nn + z * hv[o];
        h_out[(size_t)n * H + o] = ho[o];
    }
    if (hbf) {
        unsigned w0 = pack2(ho[0], ho[1]), w1 = pack2(ho[2], ho[3]), w2 = pack2(ho[4], ho[5]),
                 w3 = pack2(ho[6], ho[7]), w4 = pack2(ho[8], ho[9]);
        unsigned char* ob = hbf + (size_t)n * 20;
        *(uint4u*)ob = (uint4u){w0, w1, w2, w3};
        *(unsigned int*)(ob + 16) = w4;
    }
}

static inline size_t align256(size_t x) { return (x + 255) & ~(size_t)255; }

extern "C" void kernel_launch(void* const* d_in, const int* in_sizes, int n_in,
                              void* d_out, int out_size, void* d_ws, size_t ws_size,
                              hipStream_t stream) {
    const float* node_features = (const float*)d_in[0];
    const int*   edges         = (const int*)d_in[1];
    const float* W1 = (const float*)d_in[2];
    const float* b1 = (const float*)d_in[3];
    const float* W2 = (const float*)d_in[4];
    const float* b2 = (const float*)d_in[5];
    const float* W3 = (const float*)d_in[6];
    const float* b3 = (const float*)d_in[7];
    const float* W_ih = (const float*)d_in[8];
    const float* b_ih = (const float*)d_in[9];
    const float* W_hh = (const float*)d_in[10];
    const float* b_hh = (const float*)d_in[11];

    char* ws = (char*)d_ws;
    size_t off = 0;
    float* a = (float*)(ws + off);          off = align256(off + (size_t)N_NODES * H * sizeof(float));
    long long* pairsLL = (long long*)(ws + off);  off = align256(off + (size_t)E2 * sizeof(long long));
    size_t coff = off;
    int* cntmat = (int*)(ws + coff);              size_t c1 = align256(coff + (size_t)NBKT * NCHUNK * sizeof(int));
    int* offmat = (int*)(ws + c1);                size_t c2 = align256(c1 + (size_t)NBKT * NCHUNK * sizeof(int));
    int* totals = (int*)(ws + c2);                size_t c3 = align256(c2 + (size_t)NBKT * sizeof(int));
    int* bases  = (int*)(ws + c3);                size_t c4 = align256(c3 + (size_t)NBKT * sizeof(int));
    int* done   = (int*)(ws + c4);                size_t c5 = align256(c4 + 256);
    unsigned char* hbf = (unsigned char*)(ws + coff);  size_t h1 = align256(coff + (size_t)N_NODES * 20);
    unsigned char* wbuf = (unsigned char*)(ws + h1);   size_t h2 = align256(h1 + 14400);
    size_t need = (c5 > h2) ? c5 : h2;
    const bool use_fast = (ws_size >= need);
    // hbf/wbuf overwrite the counting-sort scratch; prep_convert runs AFTER
    // bucketsort (last consumer of totals/bases) -> stream-ordered, safe.

    float* hbuf = (float*)d_out;
    const int edge_blocks = E2 / 256;                 // 12500
    const int node_blocks = NODE_BLOCKS;              // 391

    if (use_fast) {
        binhist_kernel<<<NCHUNK, 256, 0, stream>>>(edges, cntmat, done);
        bucketscan_kernel<<<NBKT, 256, 0, stream>>>(cntmat, offmat, totals, bases, done);
        binscatter_kernel<<<NCHUNK, 256, 0, stream>>>(edges, offmat, bases, pairsLL);
        bucketsort_kernel<<<NBKT, 256, 0, stream>>>(totals, bases, pairsLL);
        prep_convert_kernel<<<node_blocks + 4, 256, 0, stream>>>(
            node_features, hbf, a, W1, b1, W2, W3, b3, wbuf);
    } else {
        hipMemsetAsync(a, 0, (size_t)N_NODES * H * sizeof(float), stream);
    }

    for (int it = 0; it < 3; ++it) {
        const float* hin = (it == 0) ? node_features : hbuf;
        if (use_fast) {
            edge_mlp_mfma2_kernel<<<edge_blocks, 256, 0, stream>>>(
                hbf, pairsLL, wbuf, b2, a);
        } else {
            edge_mlp_kernel<<<edge_blocks, 256, 0, stream>>>(
                hin, edges, W1, b1, W2, b2, W3, b3, a);
        }
        gru_kernel<<<node_blocks, 256, 0, stream>>>(
            hin, a, hbuf, W_ih, b_ih, W_hh, b_hh, use_fast ? hbf : (unsigned char*)nullptr);
    }
}

// Round 17
// 357.416 us; speedup vs baseline: 1.5091x; 1.5091x over previous
//
#include <hip/hip_runtime.h>
#include <hip/hip_bf16.h>
#include <math.h>

#define N_NODES 100000
#define N_EDGES 1600000
#define H 10
#define HID 64
#define E2 (2 * N_EDGES)          // 3,200,000

// two-level counting sort: 391 buckets of 256 nodes (b = src >> 8)
#define NBKT 391                  // ceil(100000/256)
#define NCHUNK 256
#define CHUNK (E2 / NCHUNK)       // 12500 exact
#define BKT_CAP 12032             // LDS staging cap (mean 8192, sigma ~90)

typedef __attribute__((ext_vector_type(8))) short short8;
typedef __attribute__((ext_vector_type(4))) float f32x4;
typedef __attribute__((ext_vector_type(2))) unsigned int uint2v;
typedef __attribute__((ext_vector_type(4))) unsigned int uint4v;
typedef unsigned int uint4u __attribute__((ext_vector_type(4), aligned(4)));

#define MFMA16(a, b, c) __builtin_amdgcn_mfma_f32_16x16x32_bf16((a), (b), (c), 0, 0, 0)

__device__ __forceinline__ float sigmoidf_(float x) {
    return 1.0f / (1.0f + __expf(-x));
}
__device__ __forceinline__ float tanhf_(float x) {
    float ax = fabsf(x);
    float t = 1.0f - 2.0f / (__expf(2.0f * ax) + 1.0f);
    return copysignf(t, x);
}
__device__ __forceinline__ unsigned short f2bf(float f) {
    union { __hip_bfloat16 b; unsigned short u; } cv;
    cv.b = __float2bfloat16(f);   // RNE, NaN-safe (cold paths only)
    return cv.u;
}
__device__ __forceinline__ unsigned pack2(float lo, float hi) {
    return (unsigned)f2bf(lo) | ((unsigned)f2bf(hi) << 16);
}
// hot-path packed cvt: 1 inst, RNE; inputs guaranteed finite (post-relu)
__device__ __forceinline__ unsigned cvt_pk(float lo, float hi) {
    unsigned r;
    asm("v_cvt_pk_bf16_f32 %0, %1, %2" : "=v"(r) : "v"(lo), "v"(hi));
    return r;
}
__device__ __forceinline__ int2 ll2int2(long long v) {
    int2 r;
    r.x = (int)(v & 0xffffffffll);   // src in low word
    r.y = (int)(v >> 32);            // dst in high word
    return r;
}

// ---------------- CSR build: deterministic counting sort --------------------

__global__ __launch_bounds__(256) void binhist_kernel(
    const int* __restrict__ edges, int* __restrict__ cntmat)
{
    __shared__ int cnt[NBKT];
    for (int i = threadIdx.x; i < NBKT; i += 256) cnt[i] = 0;
    __syncthreads();
    const int c = blockIdx.x, lo = c * CHUNK;
    for (int i = threadIdx.x; i < CHUNK; i += 256) {
        int s = edges[lo + i];
        atomicAdd(&cnt[s >> 8], 1);
    }
    __syncthreads();
    for (int i = threadIdx.x; i < NBKT; i += 256) cntmat[i * NCHUNK + c] = cnt[i];
}

__global__ __launch_bounds__(256) void bucketscan_kernel(
    const int* __restrict__ cntmat, int* __restrict__ offmat, int* __restrict__ totals)
{
    __shared__ int s[NCHUNK];
    const int b = blockIdx.x, tid = threadIdx.x;
    int v = cntmat[b * NCHUNK + tid];
    s[tid] = v;
    __syncthreads();
    for (int off = 1; off < 256; off <<= 1) {
        int t = (tid >= off) ? s[tid - off] : 0;
        __syncthreads();
        s[tid] += t;
        __syncthreads();
    }
    offmat[b * NCHUNK + tid] = s[tid] - v;
    if (tid == 255) totals[b] = s[255];
}

__global__ __launch_bounds__(512) void basescan_kernel(
    const int* __restrict__ totals, int* __restrict__ bases)
{
    __shared__ int s[512];
    const int tid = threadIdx.x;
    int v = (tid < NBKT) ? totals[tid] : 0;
    s[tid] = v;
    __syncthreads();
    for (int off = 1; off < 512; off <<= 1) {
        int t = (tid >= off) ? s[tid - off] : 0;
        __syncthreads();
        s[tid] += t;
        __syncthreads();
    }
    if (tid < NBKT) bases[tid] = s[tid] - v;
}

__global__ __launch_bounds__(256) void binscatter_kernel(
    const int* __restrict__ edges, const int* __restrict__ offmat,
    const int* __restrict__ bases, long long* __restrict__ pairsLL)
{
    __shared__ int cursor[NBKT];
    const int c = blockIdx.x, lo = c * CHUNK;
    for (int i = threadIdx.x; i < NBKT; i += 256)
        cursor[i] = bases[i] + offmat[i * NCHUNK + c];
    __syncthreads();
    for (int i = threadIdx.x; i < CHUNK; i += 256) {
        int e = lo + i;
        int s = edges[e];
        int d = (e < N_EDGES) ? edges[e + N_EDGES] : edges[e - N_EDGES];
        int pos = atomicAdd(&cursor[s >> 8], 1);   // LDS atomic
        pairsLL[pos] = (long long)(unsigned)s | ((long long)d << 32);
    }
}

__global__ __launch_bounds__(256) void bucketsort_kernel(
    const int* __restrict__ totals, const int* __restrict__ bases,
    long long* __restrict__ pairsLL)
{
    __shared__ long long sE[BKT_CAP];
    __shared__ int cnt[256];
    __shared__ int cur[256];
    const int b = blockIdx.x, tid = threadIdx.x;
    const int tot = totals[b], base = bases[b];
    if (tot > BKT_CAP) return;   // unsorted bucket still CORRECT (order-agnostic reduce)
    for (int i = tid; i < tot; i += 256) sE[i] = pairsLL[base + i];
    cnt[tid] = 0;
    __syncthreads();
    for (int i = tid; i < tot; i += 256)
        atomicAdd(&cnt[((int)sE[i]) & 255], 1);
    __syncthreads();
    int v = cnt[tid];
    cur[tid] = v;
    __syncthreads();
    for (int off = 1; off < 256; off <<= 1) {
        int t = (tid >= off) ? cur[tid - off] : 0;
        __syncthreads();
        cur[tid] += t;
        __syncthreads();
    }
    cnt[tid] = cur[tid] - v;
    __syncthreads();
    for (int i = tid; i < tot; i += 256) {
        long long e = sE[i];
        int r = atomicAdd(&cnt[((int)e) & 255], 1);
        pairsLL[base + r] = e;
    }
}

// ---------------- one-time precompute ---------------------------------------

#define WBUF_B3_OFF 14336   // 14*64*16

__global__ __launch_bounds__(256) void prep_weights_kernel(
    const float* __restrict__ W1, const float* __restrict__ b1,
    const float* __restrict__ W2,
    const float* __restrict__ W3, const float* __restrict__ b3,
    unsigned char* __restrict__ wbuf)
{
    int idx = blockIdx.x * 256 + threadIdx.x;   // grid=4 -> 1024 threads
    if (idx < 896) {
        int f = idx >> 6, l = idx & 63, l15 = l & 15, lo4 = l >> 4;
        unsigned short v[8];
        #pragma unroll
        for (int i = 0; i < 8; ++i) {
            int kk = lo4 * 8 + i;
            float val = 0.0f;
            if (f < 4) {
                int row = f * 16 + l15;
                val = (kk < 20) ? W1[row * 20 + kk] : (kk == 20 ? b1[row] : 0.0f);
            } else if (f < 12) {
                int g = f - 4, nt = g >> 1, ks = g & 1;
                val = W2[(nt * 16 + l15) * 64 + ks * 32 + kk];
            } else {
                int ks = f - 12;
                val = (l15 < 10) ? W3[l15 * 64 + ks * 32 + kk] : 0.0f;
            }
            v[i] = f2bf(val);
        }
        uint4v pk = { (unsigned)v[0] | ((unsigned)v[1] << 16),
                      (unsigned)v[2] | ((unsigned)v[3] << 16),
                      (unsigned)v[4] | ((unsigned)v[5] << 16),
                      (unsigned)v[6] | ((unsigned)v[7] << 16) };
        *(uint4v*)(wbuf + (size_t)idx * 16) = pk;
    } else if (idx < 896 + 16) {
        int o = idx - 896;
        *(float*)(wbuf + WBUF_B3_OFF + o * 4) = (o < 10) ? b3[o] : 0.0f;
    }
}

__global__ __launch_bounds__(256) void convert_h_kernel(
    const float* __restrict__ h, unsigned char* __restrict__ hbf)
{
    int n = blockIdx.x * 256 + threadIdx.x;
    if (n >= N_NODES) return;
    const float* r = h + (size_t)n * 10;
    unsigned w0 = pack2(r[0], r[1]), w1 = pack2(r[2], r[3]), w2 = pack2(r[4], r[5]),
             w3 = pack2(r[6], r[7]), w4 = pack2(r[8], r[9]);
    unsigned char* o = hbf + (size_t)n * 20;
    *(uint4u*)o = (uint4u){w0, w1, w2, w3};
    *(unsigned int*)(o + 16) = w4;
}

// ---------------- MFMA edge MLP (best-known: R12 config, 90.3 us/iter) ------
// 256 threads = 4 waves; block handles 256 src-sorted edges. Wave w owns LDS
// rows [w*64, w*64+64) exclusively through gather + GEMMs + REDUCTION ->
// ZERO barriers. Segments are WAVE-local. Head list in registers via
// ballot + ds_permute. Reduction loop is WAVE-UNIFORM (all 64 lanes active
// through every __shfl). Reduce uses per-(segment,feature) b32 reads + one
// dword atomic each — f32x4 grouping (R16) tripled HBM writeback, reverted.

__global__ __launch_bounds__(256) void edge_mlp_mfma2_kernel(
    const unsigned char* __restrict__ hbf,   // [N][20B] bf16
    const long long* __restrict__ pairsLL,
    const unsigned char* __restrict__ wbuf,
    const float* __restrict__ b2,
    float* __restrict__ a)
{
    __shared__ __align__(16) unsigned char sX[256 * 128];   // exactly 32 KiB

    char* sXp = (char*)sX;
    const int t = threadIdx.x;
    const int w = t >> 6, l = t & 63, l15 = l & 15, lo4 = l >> 4;
    const int mbase = w * 64;

    short8 W1f[4], W2f[4][2], W3f[2];
    #pragma unroll
    for (int nt = 0; nt < 4; ++nt)
        W1f[nt] = *(const short8*)(wbuf + ((nt * 64 + l) << 4));
    #pragma unroll
    for (int nt = 0; nt < 4; ++nt)
        #pragma unroll
        for (int ks = 0; ks < 2; ++ks)
            W2f[nt][ks] = *(const short8*)(wbuf + (((4 + nt * 2 + ks) * 64 + l) << 4));
    #pragma unroll
    for (int ks = 0; ks < 2; ++ks)
        W3f[ks] = *(const short8*)(wbuf + (((12 + ks) * 64 + l) << 4));
    // hoisted bias fragments
    f32x4 bb2[4];
    #pragma unroll
    for (int nt = 0; nt < 4; ++nt)
        bb2[nt] = *(const f32x4*)(b2 + nt * 16 + lo4 * 4);
    const f32x4 bb3 = *(const f32x4*)((const float*)(wbuf + WBUF_B3_OFF) + lo4 * 4);

    // ---- gather
    const int k = blockIdx.x * 256 + t;
    const int2 p = ll2int2(pairsLL[k]);
    const int2 pm = ll2int2(pairsLL[(k > 0) ? (k - 1) : 0]);
    // WAVE-local heads: (l&15)==0 forces a head (bounds run <=16, covers l==0)
    const bool head = ((l & 15) == 0) || (pm.x != p.x);

    const unsigned char* sp = hbf + (size_t)p.x * 20;
    const unsigned char* dp = hbf + (size_t)p.y * 20;
    uint4u s4 = *(const uint4u*)sp;
    unsigned int st = *(const unsigned int*)(sp + 16);
    uint4u d4 = *(const uint4u*)dp;
    unsigned int dt = *(const unsigned int*)(dp + 16);

    {
        char* row = sXp + (t << 7);
        const int sw = (t & 7) << 4;
        *(uint4v*)(row + (0  ^ sw)) = (uint4v){s4.x, s4.y, s4.z, s4.w};
        *(uint4v*)(row + (16 ^ sw)) = (uint4v){st, d4.x, d4.y, d4.z};
        *(uint4v*)(row + (32 ^ sw)) = (uint4v){d4.w, dt, 0x00003F80u, 0u};
        *(uint4v*)(row + (48 ^ sw)) = (uint4v){0u, 0u, 0u, 0u};
    }
    // no barrier anywhere: wave touches only its own 64 rows

    const int srow = (l15 & 7) << 4;

    // ---- GEMM1: K=32; bias embedded in W1 col 20
    #pragma unroll
    for (int mt = 0; mt < 4; ++mt) {
        const int rb = (mbase + mt * 16 + l15) << 7;
        short8 Bf = *(const short8*)(sXp + rb + ((lo4 << 4) ^ srow));
        #pragma unroll
        for (int nt = 0; nt < 4; ++nt) {
            f32x4 acc = {0.0f, 0.0f, 0.0f, 0.0f};
            acc = MFMA16(W1f[nt], Bf, acc);
            acc[0] = fmaxf(acc[0], 0.0f); acc[1] = fmaxf(acc[1], 0.0f);
            acc[2] = fmaxf(acc[2], 0.0f); acc[3] = fmaxf(acc[3], 0.0f);
            uint2v pk = { cvt_pk(acc[0], acc[1]), cvt_pk(acc[2], acc[3]) };
            const int jy = (nt * 2 + (lo4 >> 1)) << 4;
            *(uint2v*)(sXp + rb + (jy ^ srow) + ((lo4 & 1) << 3)) = pk;
        }
    }

    // ---- GEMM2: K=64, bias b2 (hoisted frags)
    #pragma unroll
    for (int mt = 0; mt < 4; ++mt) {
        const int rb = (mbase + mt * 16 + l15) << 7;
        short8 B0 = *(const short8*)(sXp + rb + ((lo4 << 4) ^ srow));
        short8 B1 = *(const short8*)(sXp + rb + (((4 + lo4) << 4) ^ srow));
        #pragma unroll
        for (int nt = 0; nt < 4; ++nt) {
            f32x4 acc = bb2[nt];
            acc = MFMA16(W2f[nt][0], B0, acc);
            acc = MFMA16(W2f[nt][1], B1, acc);
            acc[0] = fmaxf(acc[0], 0.0f); acc[1] = fmaxf(acc[1], 0.0f);
            acc[2] = fmaxf(acc[2], 0.0f); acc[3] = fmaxf(acc[3], 0.0f);
            uint2v pk = { cvt_pk(acc[0], acc[1]), cvt_pk(acc[2], acc[3]) };
            const int jy = (nt * 2 + (lo4 >> 1)) << 4;
            *(uint2v*)(sXp + rb + (jy ^ srow) + ((lo4 & 1) << 3)) = pk;
        }
    }

    // ---- GEMM3: 16 out-feats (10 valid), K=64; f32 out to slots 0-3
    #pragma unroll
    for (int mt = 0; mt < 4; ++mt) {
        const int rb = (mbase + mt * 16 + l15) << 7;
        short8 B0 = *(const short8*)(sXp + rb + ((lo4 << 4) ^ srow));
        short8 B1 = *(const short8*)(sXp + rb + (((4 + lo4) << 4) ^ srow));
        f32x4 acc = bb3;
        acc = MFMA16(W3f[0], B0, acc);
        acc = MFMA16(W3f[1], B1, acc);
        *(f32x4*)(sXp + rb + ((lo4 << 4) ^ srow)) = acc;
    }

    // ---- wave-local segmented reduction (no barriers, wave-uniform loop)
    unsigned long long m = __ballot(head);
    const int nseg = __popcll(m);                       // wave-uniform
    const int rank = __popcll(m & ((1ull << l) - 1ull));
    // push head position to lane 'rank' (heads); non-heads push to lane 63,
    // whose value is garbage only if lane 63 isn't a rank target (never read)
    const int hp = __builtin_amdgcn_ds_permute((head ? rank : 63) << 2, l);

    const int total = nseg * 10;                        // wave-uniform (>= 40)
    const int niter = (total + 63) >> 6;                // wave-uniform
    for (int it2 = 0; it2 < niter; ++it2) {
        const int q = it2 * 64 + l;
        const bool live = (q < total);
        const int qa = live ? q : (total - 1);          // clamp: keep lane active
        const int seg = qa / 10;
        const int o = qa - seg * 10;
        const int segn = (seg + 1 < nseg) ? (seg + 1) : seg;
        const int r0 = __shfl(hp, seg);                 // all 64 lanes active
        const int rn = __shfl(hp, segn);
        const int r1 = (seg + 1 < nseg) ? rn : 64;
        const int node = __shfl(p.x, r0);
        const int obase = ((o >> 2) << 4) + ((o & 3) << 2);
        float acc = 0.0f;
        for (int r = r0; r < r1; ++r) {
            int row = mbase + r;
            acc += *(const float*)(sXp + (row << 7) + (obase ^ ((row & 7) << 4)));
        }
        if (live) atomicAdd(&a[(size_t)node * H + o], acc);
    }
}

// ---------------- fallback VALU edge kernel (no workspace) ------------------

__global__ __launch_bounds__(256) void edge_mlp_kernel(
    const float* __restrict__ h,
    const int*   __restrict__ edges,
    const float* __restrict__ W1, const float* __restrict__ b1,
    const float* __restrict__ W2, const float* __restrict__ b2,
    const float* __restrict__ W3, const float* __restrict__ b3,
    float* __restrict__ a)
{
    __shared__ float sW1T[2 * H * HID];
    __shared__ float sb1[HID];
    __shared__ float sW2[HID * HID];
    __shared__ float sb2[HID];
    __shared__ float sW3T[HID * H];
    __shared__ float sb3[H];
    for (int i = threadIdx.x; i < 2 * H * HID; i += blockDim.x) {
        int kk = i >> 6, j = i & 63;
        sW1T[i] = W1[j * (2 * H) + kk];
    }
    for (int i = threadIdx.x; i < HID * HID; i += blockDim.x) sW2[i] = W2[i];
    for (int i = threadIdx.x; i < HID * H; i += blockDim.x) {
        int j = i / H, o = i - j * H;
        sW3T[i] = W3[o * HID + j];
    }
    if (threadIdx.x < HID) { sb1[threadIdx.x] = b1[threadIdx.x]; sb2[threadIdx.x] = b2[threadIdx.x]; }
    if (threadIdx.x < H)   { sb3[threadIdx.x] = b3[threadIdx.x]; }
    __syncthreads();
    int e = blockIdx.x * blockDim.x + threadIdx.x;
    if (e >= E2) return;
    int s = edges[e];
    int d = (e < N_EDGES) ? edges[N_EDGES + e] : edges[e - N_EDGES];
    const float* hs = h + (size_t)s * H;
    const float* hd = h + (size_t)d * H;
    float m1[HID];
    #pragma unroll
    for (int j = 0; j < HID; ++j) m1[j] = sb1[j];
    for (int kk = 0; kk < H; ++kk) {
        float xs = hs[kk], xd = hd[kk];
        const float* w_s = &sW1T[kk * HID];
        const float* w_d = &sW1T[(H + kk) * HID];
        #pragma unroll
        for (int j = 0; j < HID; ++j) {
            m1[j] = fmaf(w_s[j], xs, m1[j]);
            m1[j] = fmaf(w_d[j], xd, m1[j]);
        }
    }
    #pragma unroll
    for (int j = 0; j < HID; ++j) m1[j] = fmaxf(m1[j], 0.0f);
    float out[H];
    #pragma unroll
    for (int o = 0; o < H; ++o) out[o] = sb3[o];
    for (int j = 0; j < HID; ++j) {
        float acc = sb2[j];
        const float* wv = &sW2[j * HID];
        #pragma unroll
        for (int kk = 0; kk < HID; ++kk) acc = fmaf(wv[kk], m1[kk], acc);
        acc = fmaxf(acc, 0.0f);
        const float* w3 = &sW3T[j * H];
        #pragma unroll
        for (int o = 0; o < H; ++o) out[o] = fmaf(w3[o], acc, out[o]);
    }
    float* as = a + (size_t)s * H;
    #pragma unroll
    for (int o = 0; o < H; ++o) atomicAdd(&as[o], out[o]);
}

// ---------------- GRU (+ bf16 h epilogue + a re-zero) -----------------------

__global__ __launch_bounds__(256) void gru_kernel(
    const float* __restrict__ h_in,
    float* __restrict__ a,               // read, then zeroed for next iter
    float* __restrict__ h_out,
    const float* __restrict__ W_ih, const float* __restrict__ b_ih,
    const float* __restrict__ W_hh, const float* __restrict__ b_hh,
    unsigned char* __restrict__ hbf)
{
    __shared__ float sWih[3 * H * H];
    __shared__ float sWhh[3 * H * H];
    __shared__ float sbih[3 * H];
    __shared__ float sbhh[3 * H];
    for (int i = threadIdx.x; i < 3 * H * H; i += blockDim.x) { sWih[i] = W_ih[i]; sWhh[i] = W_hh[i]; }
    if (threadIdx.x < 3 * H) { sbih[threadIdx.x] = b_ih[threadIdx.x]; sbhh[threadIdx.x] = b_hh[threadIdx.x]; }
    __syncthreads();

    int n = blockIdx.x * blockDim.x + threadIdx.x;
    if (n >= N_NODES) return;

    float av[H], hv[H];
    #pragma unroll
    for (int kk = 0; kk < H; ++kk) { av[kk] = a[(size_t)n * H + kk]; hv[kk] = h_in[(size_t)n * H + kk]; }
    #pragma unroll
    for (int kk = 0; kk < H; ++kk) a[(size_t)n * H + kk] = 0.0f;   // re-zero for next iter

    float gi[3 * H], gh[3 * H];
    #pragma unroll
    for (int g = 0; g < 3 * H; ++g) {
        float ai = sbih[g], hh = sbhh[g];
        const float* wi = &sWih[g * H];
        const float* wh = &sWhh[g * H];
        #pragma unroll
        for (int kk = 0; kk < H; ++kk) {
            ai = fmaf(wi[kk], av[kk], ai);
            hh = fmaf(wh[kk], hv[kk], hh);
        }
        gi[g] = ai; gh[g] = hh;
    }

    float ho[H];
    #pragma unroll
    for (int o = 0; o < H; ++o) {
        float r = sigmoidf_(gi[o] + gh[o]);
        float z = sigmoidf_(gi[H + o] + gh[H + o]);
        float nn = tanhf_(gi[2 * H + o] + r * gh[2 * H + o]);
        ho[o] = (1.0f - z) * nn + z * hv[o];
        h_out[(size_t)n * H + o] = ho[o];
    }
    if (hbf) {
        unsigned w0 = pack2(ho[0], ho[1]), w1 = pack2(ho[2], ho[3]), w2 = pack2(ho[4], ho[5]),
                 w3 = pack2(ho[6], ho[7]), w4 = pack2(ho[8], ho[9]);
        unsigned char* ob = hbf + (size_t)n * 20;
        *(uint4u*)ob = (uint4u){w0, w1, w2, w3};
        *(unsigned int*)(ob + 16) = w4;
    }
}

static inline size_t align256(size_t x) { return (x + 255) & ~(size_t)255; }

extern "C" void kernel_launch(void* const* d_in, const int* in_sizes, int n_in,
                              void* d_out, int out_size, void* d_ws, size_t ws_size,
                              hipStream_t stream) {
    const float* node_features = (const float*)d_in[0];
    const int*   edges         = (const int*)d_in[1];
    const float* W1 = (const float*)d_in[2];
    const float* b1 = (const float*)d_in[3];
    const float* W2 = (const float*)d_in[4];
    const float* b2 = (const float*)d_in[5];
    const float* W3 = (const float*)d_in[6];
    const float* b3 = (const float*)d_in[7];
    const float* W_ih = (const float*)d_in[8];
    const float* b_ih = (const float*)d_in[9];
    const float* W_hh = (const float*)d_in[10];
    const float* b_hh = (const float*)d_in[11];

    char* ws = (char*)d_ws;
    size_t off = 0;
    float* a = (float*)(ws + off);          off = align256(off + (size_t)N_NODES * H * sizeof(float));
    long long* pairsLL = (long long*)(ws + off);  off = align256(off + (size_t)E2 * sizeof(long long));
    size_t coff = off;
    int* cntmat = (int*)(ws + coff);              size_t c1 = align256(coff + (size_t)NBKT * NCHUNK * sizeof(int));
    int* offmat = (int*)(ws + c1);                size_t c2 = align256(c1 + (size_t)NBKT * NCHUNK * sizeof(int));
    int* totals = (int*)(ws + c2);                size_t c3 = align256(c2 + (size_t)NBKT * sizeof(int));
    int* bases  = (int*)(ws + c3);                size_t c4 = align256(c3 + (size_t)NBKT * sizeof(int));
    unsigned char* hbf = (unsigned char*)(ws + coff);  size_t h1 = align256(coff + (size_t)N_NODES * 20);
    unsigned char* wbuf = (unsigned char*)(ws + h1);   size_t h2 = align256(h1 + 14400);
    size_t need = (c4 > h2) ? c4 : h2;
    const bool use_fast = (ws_size >= need);

    float* hbuf = (float*)d_out;
    const int edge_blocks = E2 / 256;                 // 12500
    const int node_blocks = (N_NODES + 255) / 256;    // 391

    if (use_fast) {
        binhist_kernel<<<NCHUNK, 256, 0, stream>>>(edges, cntmat);
        bucketscan_kernel<<<NBKT, 256, 0, stream>>>(cntmat, offmat, totals);
        basescan_kernel<<<1, 512, 0, stream>>>(totals, bases);
        binscatter_kernel<<<NCHUNK, 256, 0, stream>>>(edges, offmat, bases, pairsLL);
        bucketsort_kernel<<<NBKT, 256, 0, stream>>>(totals, bases, pairsLL);
        prep_weights_kernel<<<4, 256, 0, stream>>>(W1, b1, W2, W3, b3, wbuf);
        convert_h_kernel<<<node_blocks, 256, 0, stream>>>(node_features, hbf);
    }

    // one memset clears the 0xAA poison; gru re-zeros `a` each iteration
    hipMemsetAsync(a, 0, (size_t)N_NODES * H * sizeof(float), stream);

    for (int it = 0; it < 3; ++it) {
        const float* hin = (it == 0) ? node_features : hbuf;
        if (use_fast) {
            edge_mlp_mfma2_kernel<<<edge_blocks, 256, 0, stream>>>(
                hbf, pairsLL, wbuf, b2, a);
        } else {
            edge_mlp_kernel<<<edge_blocks, 256, 0, stream>>>(
                hin, edges, W1, b1, W2, b2, W3, b3, a);
        }
        gru_kernel<<<node_blocks, 256, 0, stream>>>(
            hin, a, hbuf, W_ih, b_ih, W_hh, b_hh, use_fast ? hbf : (unsigned char*)nullptr);
    }
}